// Round 18
// baseline (404.291 us; speedup 1.0000x reference)
//
#include <hip/hip_runtime.h>
#include <hip/hip_fp16.h>

#define N_NODES 100000
#define N_EDGES 1000000
#define N_GRAPHS 1000
#define EMBED 64
#define OUT_DIM 128
#define BN_EPS 1e-5f
#define NBINS 391                          // dst>>8 -> 256 nodes per bin
#define NSCB 512                           // scatter blocks (fixed edge ranges)
#define EPB ((N_EDGES + NSCB - 1) / NSCB)  // 1954 edges per block
#define NTILES (N_NODES / 16)              // 6250 exact

typedef _Float16 half8 __attribute__((ext_vector_type(8)));
typedef float floatx4 __attribute__((ext_vector_type(4)));

// ---------------- one-time structure kernels ----------------

// writes fp32 h and fp16 mirror; also builds graph boundaries (gid sorted)
__global__ void embed_kernel(const int* __restrict__ nfeat,
                             const float* __restrict__ atom_embed,
                             float4* __restrict__ h4,
                             __half* __restrict__ hh,
                             const int* __restrict__ gid,
                             int* __restrict__ gstart) {
    int idx = blockIdx.x * blockDim.x + threadIdx.x;   // one float4 each
    if (idx <= N_NODES) {   // folded gbound
        int cur  = (idx < N_NODES) ? gid[idx] : N_GRAPHS;
        int prev = (idx == 0) ? -1 : gid[idx - 1];
        for (int g = prev + 1; g <= cur; ++g) gstart[g] = idx;
    }
    if (idx >= N_NODES * 16) return;
    int v = idx >> 4, q = idx & 15;
    const float4* ae = (const float4*)atom_embed;
    float4 val = ae[nfeat[v] * 16 + q];
    h4[idx] = val;
    __half2 m0 = __floats2half2_rn(val.x, val.y);
    __half2 m1 = __floats2half2_rn(val.z, val.w);
    uint2 packed;
    packed.x = *(unsigned*)&m0;
    packed.y = *(unsigned*)&m1;
    ((uint2*)hh)[idx] = packed;
}

// per-block LDS histogram of its fixed edge range -> blockhist[bin][block]
__global__ void hist2_kernel(const int* __restrict__ dst, int* __restrict__ blockhist) {
    __shared__ int hist[NBINS];
    for (int i = threadIdx.x; i < NBINS; i += 256) hist[i] = 0;
    __syncthreads();
    int b = blockIdx.x;
    int e0 = b * EPB, e1 = min(e0 + EPB, N_EDGES);
    for (int e = e0 + threadIdx.x; e < e1; e += 256)
        atomicAdd(&hist[dst[e] >> 8], 1);
    __syncthreads();
    for (int i = threadIdx.x; i < NBINS; i += 256)
        blockhist[i * NSCB + b] = hist[i];
}

// one block per bin: exclusive scan of its 512 block-counts -> gofs; total per bin
__global__ void binreduce_kernel(const int* __restrict__ blockhist,
                                 int* __restrict__ gofs, int* __restrict__ total) {
    __shared__ int sm[NSCB];
    int bin = blockIdx.x;
    int i = threadIdx.x;   // 0..511
    int orig = blockhist[bin * NSCB + i];
    sm[i] = orig;
    __syncthreads();
    for (int off = 1; off < NSCB; off <<= 1) {
        int val = sm[i];
        if (i >= off) val += sm[i - off];
        __syncthreads();
        sm[i] = val;
        __syncthreads();
    }
    gofs[bin * NSCB + i] = sm[i] - orig;   // exclusive within bin
    if (i == NSCB - 1) total[bin] = sm[i];
}

// scan bin totals -> binoff (exclusive); zeroes BN stats; packs W frags
__global__ void binscan_kernel(const int* __restrict__ total,
                               int* __restrict__ binoff, float* __restrict__ stats,
                               const float* __restrict__ conv_W,
                               _Float16* __restrict__ wfrag) {
    __shared__ int sm[1024];
    int i = threadIdx.x;
    if (i < 6 * EMBED) stats[i] = 0.0f;
    // folded wpack: 3 layers x 512 slots
    for (int s = i; s < 3 * 512; s += 1024) {
        int L = s >> 9, slot = s & 511;
        int lane = slot & 63;
        int f = slot >> 6;          // nt*2+kh
        int nt = f >> 1, kh = f & 1;
        int n  = nt * 16 + (lane & 15);
        int k0 = kh * 32 + (lane >> 4) * 8;
        const float* W = conv_W + L * 4096;
        _Float16* out = wfrag + L * 4096;
#pragma unroll
        for (int j = 0; j < 8; ++j)
            out[slot * 8 + j] = (_Float16)W[(k0 + j) * 64 + n];
    }
    int orig = (i < NBINS) ? total[i] : 0;
    sm[i] = orig;
    __syncthreads();
    for (int off = 1; off < 1024; off <<= 1) {
        int val = sm[i];
        if (i >= off) val += sm[i - off];
        __syncthreads();
        sm[i] = val;
        __syncthreads();
    }
    if (i < NBINS) binoff[i] = sm[i] - orig;
    if (i == 0) binoff[NBINS] = N_EDGES;
}

// deterministic multisplit scatter: LDS cursors seeded from binoff+gofs.
// ZERO global atomics (R12: contention, not traffic, is the cost).
// record = src(17b) | efeat(3b)<<17 | dstlocal(8b)<<20
__global__ void binscatter_kernel(const int* __restrict__ src, const int* __restrict__ dst,
                                  const int* __restrict__ efeat,
                                  const int* __restrict__ binoff, const int* __restrict__ gofs,
                                  unsigned* __restrict__ binned) {
    __shared__ int cur[NBINS];
    int b = blockIdx.x;
    for (int i = threadIdx.x; i < NBINS; i += 256)
        cur[i] = binoff[i] + gofs[i * NSCB + b];
    __syncthreads();
    int e0 = b * EPB, e1 = min(e0 + EPB, N_EDGES);
    for (int e = e0 + threadIdx.x; e < e1; e += 256) {
        int t = dst[e];
        int bin = t >> 8;
        int pos = atomicAdd(&cur[bin], 1);   // LDS atomic
        binned[pos] = (unsigned)src[e] | ((unsigned)efeat[e] << 17)
                    | ((unsigned)(t & 255) << 20);
    }
}

// one block per bin: local deg count + local scan -> rowptr slice + ebuf region
__global__ void bincsr_kernel(const unsigned* __restrict__ binned,
                              const int* __restrict__ binoff,
                              int* __restrict__ rowptr,
                              unsigned* __restrict__ ebuf) {
    __shared__ int cnt[256];
    __shared__ int sc[256];
    int b = blockIdx.x;
    int tid = threadIdx.x;
    int base = binoff[b], end = binoff[b + 1];

    cnt[tid] = 0;
    __syncthreads();

    for (int i = base + tid; i < end; i += 256)
        atomicAdd(&cnt[binned[i] >> 20], 1);
    __syncthreads();

    sc[tid] = cnt[tid];
    __syncthreads();
    for (int off = 1; off < 256; off <<= 1) {
        int val = sc[tid];
        if (tid >= off) val += sc[tid - off];
        __syncthreads();
        sc[tid] = val;
        __syncthreads();
    }
    {
        int excl = sc[tid] - cnt[tid];
        int v = b * 256 + tid;
        if (v < N_NODES) rowptr[v] = base + excl;
        cnt[tid] = excl;   // becomes running cursor
    }
    if (b == 0 && tid == 0) rowptr[N_NODES] = N_EDGES;
    __syncthreads();

    for (int i = base + tid; i < end; i += 256) {
        unsigned rec = binned[i];
        int dl = rec >> 20;
        int pos = base + atomicAdd(&cnt[dl], 1);
        // final payload format for gather: src(17b) | efeat<<20
        ebuf[pos] = (rec & 0x1FFFFu) | (((rec >> 17) & 0x7u) << 20);
    }
}

// ---------------- per-layer kernels ----------------

// Gather: EIGHTH-wave per node (8 lanes x uint4 = 128B fp16 row per edge),
// 4 interleaved chains -> ~32 lines in flight per wave (2x R17 quarter-wave;
// concurrency ladder R8->R9->R10: 75->63->55us says the line-service wall
// still responds to depth). Writes t in fp16 for MFMA gemm.
__launch_bounds__(256, 6)
__global__ void gather_kernel(const int* __restrict__ rowptr,
                              const unsigned* __restrict__ ebuf,
                              const float* __restrict__ bond,    // [5,64]
                              const __half* __restrict__ hh,     // fp16 mirror
                              const float* __restrict__ hmast,   // fp32 master
                              __half* __restrict__ t16) {
    __shared__ float bond_s[5 * EMBED];
    for (int i = threadIdx.x; i < 5 * EMBED; i += 256) bond_s[i] = bond[i];
    __syncthreads();

    int sl = threadIdx.x & 7;     // uint4 slot: dims 8sl..8sl+7
    int d0 = sl * 8;
    int g8 = (blockIdx.x * 256 + threadIdx.x) >> 3;   // global eighth id
    int n8 = (gridDim.x * 256) >> 3;
    const uint4* hhq = (const uint4*)hh;    // 8 uint4 per node row

    for (int v = g8; v < N_NODES; v += n8) {
        int rb = rowptr[v], re = rowptr[v + 1];
        float4 s0a = {0,0,0,0}, s0b = {0,0,0,0};
        float4 s1a = {0,0,0,0}, s1b = {0,0,0,0};
        float4 s2a = {0,0,0,0}, s2b = {0,0,0,0};
        float4 s3a = {0,0,0,0}, s3b = {0,0,0,0};
        int e = rb;
        for (; e + 4 <= re; e += 4) {
            unsigned p0 = ebuf[e + 0];
            unsigned p1 = ebuf[e + 1];
            unsigned p2 = ebuf[e + 2];
            unsigned p3 = ebuf[e + 3];
            uint4 g0 = hhq[(size_t)(p0 & 0xFFFFFu) * 8 + sl];
            uint4 g1 = hhq[(size_t)(p1 & 0xFFFFFu) * 8 + sl];
            uint4 g2 = hhq[(size_t)(p2 & 0xFFFFFu) * 8 + sl];
            uint4 g3 = hhq[(size_t)(p3 & 0xFFFFFu) * 8 + sl];
            const float* c0 = &bond_s[(p0 >> 20) * EMBED + d0];
            const float* c1 = &bond_s[(p1 >> 20) * EMBED + d0];
            const float* c2 = &bond_s[(p2 >> 20) * EMBED + d0];
            const float* c3 = &bond_s[(p3 >> 20) * EMBED + d0];
            float2 f0a = __half22float2(*(const __half2*)&g0.x);
            float2 f0b = __half22float2(*(const __half2*)&g0.y);
            float2 f0c = __half22float2(*(const __half2*)&g0.z);
            float2 f0d = __half22float2(*(const __half2*)&g0.w);
            float2 f1a = __half22float2(*(const __half2*)&g1.x);
            float2 f1b = __half22float2(*(const __half2*)&g1.y);
            float2 f1c = __half22float2(*(const __half2*)&g1.z);
            float2 f1d = __half22float2(*(const __half2*)&g1.w);
            float2 f2a = __half22float2(*(const __half2*)&g2.x);
            float2 f2b = __half22float2(*(const __half2*)&g2.y);
            float2 f2c = __half22float2(*(const __half2*)&g2.z);
            float2 f2d = __half22float2(*(const __half2*)&g2.w);
            float2 f3a = __half22float2(*(const __half2*)&g3.x);
            float2 f3b = __half22float2(*(const __half2*)&g3.y);
            float2 f3c = __half22float2(*(const __half2*)&g3.z);
            float2 f3d = __half22float2(*(const __half2*)&g3.w);
            s0a.x += fmaxf(f0a.x + c0[0], 0.f); s0a.y += fmaxf(f0a.y + c0[1], 0.f);
            s0a.z += fmaxf(f0b.x + c0[2], 0.f); s0a.w += fmaxf(f0b.y + c0[3], 0.f);
            s0b.x += fmaxf(f0c.x + c0[4], 0.f); s0b.y += fmaxf(f0c.y + c0[5], 0.f);
            s0b.z += fmaxf(f0d.x + c0[6], 0.f); s0b.w += fmaxf(f0d.y + c0[7], 0.f);
            s1a.x += fmaxf(f1a.x + c1[0], 0.f); s1a.y += fmaxf(f1a.y + c1[1], 0.f);
            s1a.z += fmaxf(f1b.x + c1[2], 0.f); s1a.w += fmaxf(f1b.y + c1[3], 0.f);
            s1b.x += fmaxf(f1c.x + c1[4], 0.f); s1b.y += fmaxf(f1c.y + c1[5], 0.f);
            s1b.z += fmaxf(f1d.x + c1[6], 0.f); s1b.w += fmaxf(f1d.y + c1[7], 0.f);
            s2a.x += fmaxf(f2a.x + c2[0], 0.f); s2a.y += fmaxf(f2a.y + c2[1], 0.f);
            s2a.z += fmaxf(f2b.x + c2[2], 0.f); s2a.w += fmaxf(f2b.y + c2[3], 0.f);
            s2b.x += fmaxf(f2c.x + c2[4], 0.f); s2b.y += fmaxf(f2c.y + c2[5], 0.f);
            s2b.z += fmaxf(f2d.x + c2[6], 0.f); s2b.w += fmaxf(f2d.y + c2[7], 0.f);
            s3a.x += fmaxf(f3a.x + c3[0], 0.f); s3a.y += fmaxf(f3a.y + c3[1], 0.f);
            s3a.z += fmaxf(f3b.x + c3[2], 0.f); s3a.w += fmaxf(f3b.y + c3[3], 0.f);
            s3b.x += fmaxf(f3c.x + c3[4], 0.f); s3b.y += fmaxf(f3c.y + c3[5], 0.f);
            s3b.z += fmaxf(f3d.x + c3[6], 0.f); s3b.w += fmaxf(f3d.y + c3[7], 0.f);
        }
        for (; e < re; ++e) {
            unsigned p = ebuf[e];
            uint4 g = hhq[(size_t)(p & 0xFFFFFu) * 8 + sl];
            const float* c = &bond_s[(p >> 20) * EMBED + d0];
            float2 fa = __half22float2(*(const __half2*)&g.x);
            float2 fb = __half22float2(*(const __half2*)&g.y);
            float2 fc = __half22float2(*(const __half2*)&g.z);
            float2 fd = __half22float2(*(const __half2*)&g.w);
            s0a.x += fmaxf(fa.x + c[0], 0.f); s0a.y += fmaxf(fa.y + c[1], 0.f);
            s0a.z += fmaxf(fb.x + c[2], 0.f); s0a.w += fmaxf(fb.y + c[3], 0.f);
            s0b.x += fmaxf(fc.x + c[4], 0.f); s0b.y += fmaxf(fc.y + c[5], 0.f);
            s0b.z += fmaxf(fd.x + c[6], 0.f); s0b.w += fmaxf(fd.y + c[7], 0.f);
        }
        float inv = 1.0f / fmaxf((float)(re - rb), 1.0f);
        float4 h0 = ((const float4*)hmast)[(size_t)v * 16 + sl * 2];
        float4 h1 = ((const float4*)hmast)[(size_t)v * 16 + sl * 2 + 1];
        float t0 = (s0a.x + s1a.x + s2a.x + s3a.x) * inv + h0.x;
        float t1 = (s0a.y + s1a.y + s2a.y + s3a.y) * inv + h0.y;
        float t2 = (s0a.z + s1a.z + s2a.z + s3a.z) * inv + h0.z;
        float t3 = (s0a.w + s1a.w + s2a.w + s3a.w) * inv + h0.w;
        float t4 = (s0b.x + s1b.x + s2b.x + s3b.x) * inv + h1.x;
        float t5 = (s0b.y + s1b.y + s2b.y + s3b.y) * inv + h1.y;
        float t6 = (s0b.z + s1b.z + s2b.z + s3b.z) * inv + h1.z;
        float t7 = (s0b.w + s1b.w + s2b.w + s3b.w) * inv + h1.w;
        __half2 m0 = __floats2half2_rn(t0, t1);
        __half2 m1 = __floats2half2_rn(t2, t3);
        __half2 m2 = __floats2half2_rn(t4, t5);
        __half2 m3 = __floats2half2_rn(t6, t7);
        uint4 packed;
        packed.x = *(unsigned*)&m0;
        packed.y = *(unsigned*)&m1;
        packed.z = *(unsigned*)&m2;
        packed.w = *(unsigned*)&m3;
        ((uint4*)t16)[(size_t)v * 8 + sl] = packed;
    }
}

// MFMA GEMM: wave = 16 nodes; W fragments loop-invariant in registers
// (R13-R15 were all ~50us bound on W operand re-fetch through LDS/L1).
// h_pre stored fp16. C/D layout: col=lane&15, row=(lane>>4)*4+reg [m89].
__launch_bounds__(256)
__global__ void gemm_mfma_kernel(const _Float16* __restrict__ t16,
                                 const _Float16* __restrict__ wfrag,  // packed
                                 const float* __restrict__ bias,
                                 __half* __restrict__ h_pre16,
                                 float* __restrict__ colsum,
                                 float* __restrict__ colsq) {
    __shared__ float red[4][8][16];

    int lane = threadIdx.x & 63;
    int wblk = threadIdx.x >> 6;
    int quad = lane >> 4;
    int col  = lane & 15;

    half8 bf[4][2];
#pragma unroll
    for (int nt = 0; nt < 4; ++nt)
#pragma unroll
        for (int kh = 0; kh < 2; ++kh)
            bf[nt][kh] = *(const half8*)(wfrag + ((size_t)(nt * 2 + kh) * 64 + lane) * 8);

    float bj[4];
#pragma unroll
    for (int nt = 0; nt < 4; ++nt) bj[nt] = bias[nt * 16 + col];

    float lsum[4] = {0.f, 0.f, 0.f, 0.f};
    float lsq [4] = {0.f, 0.f, 0.f, 0.f};

    for (int tile = blockIdx.x * 4 + wblk; tile < NTILES; tile += gridDim.x * 4) {
        int base = tile * 16;
        const _Float16* arow = t16 + (size_t)(base + col) * 64 + quad * 8;
        half8 a0 = *(const half8*)(arow);
        half8 a1 = *(const half8*)(arow + 32);

#pragma unroll
        for (int nt = 0; nt < 4; ++nt) {
            floatx4 c = {bj[nt], bj[nt], bj[nt], bj[nt]};
            c = __builtin_amdgcn_mfma_f32_16x16x32_f16(a0, bf[nt][0], c, 0, 0, 0);
            c = __builtin_amdgcn_mfma_f32_16x16x32_f16(a1, bf[nt][1], c, 0, 0, 0);
#pragma unroll
            for (int r = 0; r < 4; ++r) {
                float val = c[r];
                h_pre16[(size_t)(base + quad * 4 + r) * 64 + nt * 16 + col] = __float2half(val);
                lsum[nt] += val;
                lsq[nt]  += val * val;
            }
        }
    }

#pragma unroll
    for (int nt = 0; nt < 4; ++nt) {
        lsum[nt] += __shfl_xor(lsum[nt], 16); lsum[nt] += __shfl_xor(lsum[nt], 32);
        lsq[nt]  += __shfl_xor(lsq[nt], 16);  lsq[nt]  += __shfl_xor(lsq[nt], 32);
    }
    if (lane < 16) {
#pragma unroll
        for (int nt = 0; nt < 4; ++nt) {
            red[wblk][nt * 2 + 0][lane] = lsum[nt];
            red[wblk][nt * 2 + 1][lane] = lsq[nt];
        }
    }
    __syncthreads();
    if (threadIdx.x < 128) {
        int f = threadIdx.x >> 4, l = threadIdx.x & 15;
        float s = red[0][f][l] + red[1][f][l] + red[2][f][l] + red[3][f][l];
        int nt = f >> 1;
        if ((f & 1) == 0) atomicAdd(&colsum[nt * 16 + l], s);
        else              atomicAdd(&colsq[nt * 16 + l], s);
    }
}

// batchnorm + relu + residual (layers 0,1): reads fp16 h_pre, updates fp32 h + fp16 mirror
__global__ void bn_kernel(const __half* __restrict__ h_pre16,
                          const float* __restrict__ colsum,
                          const float* __restrict__ colsq,
                          const float* __restrict__ gamma,
                          const float* __restrict__ beta,
                          float4* __restrict__ h4,
                          __half* __restrict__ hh) {
    int idx = blockIdx.x * blockDim.x + threadIdx.x;   // 4 dims each
    if (idx >= N_NODES * 16) return;
    int q = idx & 15;            // dims 4q..4q+3
    const float invN = 1.0f / (float)N_NODES;
    uint2 pr = ((const uint2*)h_pre16)[idx];
    float2 pa = __half22float2(*(const __half2*)&pr.x);
    float2 pb = __half22float2(*(const __half2*)&pr.y);
    float4 r = h4[idx];
    float o[4] = {pa.x, pa.y, pb.x, pb.y};
    float rr[4] = {r.x, r.y, r.z, r.w};
#pragma unroll
    for (int c = 0; c < 4; ++c) {
        int j = q * 4 + c;
        float mu  = colsum[j] * invN;
        float var = colsq[j] * invN - mu * mu;
        float inv = rsqrtf(var + BN_EPS);
        float y = (o[c] - mu) * inv * gamma[j] + beta[j];
        y = fmaxf(y, 0.0f);                  // layers 0,1 always relu
        o[c] = y + rr[c];
    }
    float4 res = {o[0], o[1], o[2], o[3]};
    h4[idx] = res;
    __half2 m0 = __floats2half2_rn(res.x, res.y);
    __half2 m1 = __floats2half2_rn(res.z, res.w);
    uint2 packed;
    packed.x = *(unsigned*)&m0;
    packed.y = *(unsigned*)&m1;
    ((uint2*)hh)[idx] = packed;
}

// fused layer-2 bn + pool + pred: one block (128 threads) per graph.
__global__ void poolpred_kernel(const int* __restrict__ gstart,
                                const __half* __restrict__ h_pre16,
                                const float* __restrict__ h,
                                const float* __restrict__ colsum,   // layer 2 slice
                                const float* __restrict__ colsq,
                                const float* __restrict__ gamma,
                                const float* __restrict__ beta,
                                const float* __restrict__ W,   // [64,128]
                                const float* __restrict__ b,   // [128]
                                float* __restrict__ out) {
    __shared__ float gm[EMBED];
    int g = blockIdx.x;
    int j = threadIdx.x;  // 0..127
    int nb = gstart[g], ne = gstart[g + 1];
    if (j < EMBED) {
        const float invN = 1.0f / (float)N_NODES;
        float mu  = colsum[j] * invN;
        float var = colsq[j] * invN - mu * mu;
        float inv = rsqrtf(var + BN_EPS);
        float gam = gamma[j], bet = beta[j];
        float s = 0.0f;
        for (int v = nb; v < ne; ++v) {
            float p = __half2float(h_pre16[(size_t)v * EMBED + j]);
            float y = (p - mu) * inv * gam + bet;       // no relu on last layer
            s += y + h[(size_t)v * EMBED + j];
        }
        gm[j] = s / fmaxf((float)(ne - nb), 1.0f);
    }
    __syncthreads();
    float acc = b[j];
#pragma unroll
    for (int d = 0; d < EMBED; ++d)
        acc += gm[d] * W[d * OUT_DIM + j];
    out[g * OUT_DIM + j] = acc;
}

// ---------------- launch ----------------

extern "C" void kernel_launch(void* const* d_in, const int* in_sizes, int n_in,
                              void* d_out, int out_size, void* d_ws, size_t ws_size,
                              hipStream_t stream) {
    const int*   nfeat      = (const int*)d_in[0];
    const int*   efeat      = (const int*)d_in[1];
    const int*   src        = (const int*)d_in[2];
    const int*   dst        = (const int*)d_in[3];
    const int*   gid        = (const int*)d_in[4];
    const float* atom_embed = (const float*)d_in[5];
    const float* bond_embed = (const float*)d_in[6];  // [3,5,64]
    const float* conv_W     = (const float*)d_in[7];  // [3,64,64]
    const float* conv_b     = (const float*)d_in[8];  // [3,64]
    const float* bn_gamma   = (const float*)d_in[9];  // [3,64]
    const float* bn_beta    = (const float*)d_in[10]; // [3,64]
    const float* pred_W     = (const float*)d_in[11]; // [64,128]
    const float* pred_b     = (const float*)d_in[12]; // [128]
    float* out = (float*)d_out;

    char* wsb = (char*)d_ws;
    float*     h        = (float*)wsb;                  wsb += (size_t)N_NODES * EMBED * 4;
    __half*    h_pre16  = (__half*)wsb;                 wsb += (size_t)N_NODES * EMBED * 2;
    _Float16*  t16      = (_Float16*)wsb;               wsb += (size_t)N_NODES * EMBED * 2;
    __half*    hh       = (__half*)wsb;                 wsb += (size_t)N_NODES * EMBED * 2;
    _Float16*  wfrag    = (_Float16*)wsb;               wsb += (size_t)3 * 4096 * 2;
    unsigned*  binned   = (unsigned*)wsb;               wsb += (size_t)N_EDGES * 4;
    unsigned*  ebuf     = (unsigned*)wsb;               wsb += (size_t)N_EDGES * 4;
    int*       blockhist= (int*)wsb;                    wsb += (size_t)NBINS * NSCB * 4;
    int*       gofs     = (int*)wsb;                    wsb += (size_t)NBINS * NSCB * 4;
    int*       total    = (int*)wsb;                    wsb += (size_t)NBINS * 4;
    int*       binoff   = (int*)wsb;                    wsb += (size_t)(NBINS + 1) * 4;
    int*       rowptr   = (int*)wsb;                    wsb += (size_t)(N_NODES + 1) * 4;
    int*       gstart   = (int*)wsb;                    wsb += (size_t)(N_GRAPHS + 1) * 4;
    float*     colsum   = (float*)wsb;                  wsb += (size_t)3 * EMBED * 4;
    float*     colsq    = (float*)wsb;                  wsb += (size_t)3 * EMBED * 4;

    embed_kernel<<<(N_NODES * 16 + 255) / 256, 256, 0, stream>>>(
        nfeat, atom_embed, (float4*)h, hh, gid, gstart);
    hist2_kernel<<<NSCB, 256, 0, stream>>>(dst, blockhist);
    binreduce_kernel<<<NBINS, NSCB, 0, stream>>>(blockhist, gofs, total);
    binscan_kernel<<<1, 1024, 0, stream>>>(total, binoff, colsum, conv_W, wfrag);
    binscatter_kernel<<<NSCB, 256, 0, stream>>>(src, dst, efeat, binoff, gofs, binned);
    bincsr_kernel<<<NBINS, 256, 0, stream>>>(binned, binoff, rowptr, ebuf);

    for (int i = 0; i < 3; ++i) {
        gather_kernel<<<1536, 256, 0, stream>>>(
            rowptr, ebuf, bond_embed + i * 5 * EMBED, hh, h, (__half*)t16);
        gemm_mfma_kernel<<<1024, 256, 0, stream>>>(
            t16, wfrag + (size_t)i * 4096, conv_b + i * EMBED,
            h_pre16, colsum + i * EMBED, colsq + i * EMBED);
        if (i != 2) {
            bn_kernel<<<(N_NODES * 16 + 255) / 256, 256, 0, stream>>>(
                h_pre16, colsum + i * EMBED, colsq + i * EMBED,
                bn_gamma + i * EMBED, bn_beta + i * EMBED,
                (float4*)h, hh);
        }
    }

    poolpred_kernel<<<N_GRAPHS, OUT_DIM, 0, stream>>>(
        gstart, h_pre16, h, colsum + 2 * EMBED, colsq + 2 * EMBED,
        bn_gamma + 2 * EMBED, bn_beta + 2 * EMBED, pred_W, pred_b, out);
}

// Round 19
// 388.517 us; speedup vs baseline: 1.0406x; 1.0406x over previous
//
#include <hip/hip_runtime.h>
#include <hip/hip_fp16.h>

#define N_NODES 100000
#define N_EDGES 1000000
#define N_GRAPHS 1000
#define EMBED 64
#define OUT_DIM 128
#define BN_EPS 1e-5f
#define NBINS 782                          // dst>>7 -> 128 nodes per bin
#define NSCB 512                           // scatter blocks (fixed edge ranges)
#define EPB ((N_EDGES + NSCB - 1) / NSCB)  // 1954 edges per block
#define NTILES (N_NODES / 16)              // 6250 exact

typedef _Float16 half8 __attribute__((ext_vector_type(8)));
typedef float floatx4 __attribute__((ext_vector_type(4)));

// ---------------- one-time structure kernels ----------------

// writes fp32 h and fp16 mirror; also builds graph boundaries (gid sorted)
__global__ void embed_kernel(const int* __restrict__ nfeat,
                             const float* __restrict__ atom_embed,
                             float4* __restrict__ h4,
                             __half* __restrict__ hh,
                             const int* __restrict__ gid,
                             int* __restrict__ gstart) {
    int idx = blockIdx.x * blockDim.x + threadIdx.x;   // one float4 each
    if (idx <= N_NODES) {   // folded gbound
        int cur  = (idx < N_NODES) ? gid[idx] : N_GRAPHS;
        int prev = (idx == 0) ? -1 : gid[idx - 1];
        for (int g = prev + 1; g <= cur; ++g) gstart[g] = idx;
    }
    if (idx >= N_NODES * 16) return;
    int v = idx >> 4, q = idx & 15;
    const float4* ae = (const float4*)atom_embed;
    float4 val = ae[nfeat[v] * 16 + q];
    h4[idx] = val;
    __half2 m0 = __floats2half2_rn(val.x, val.y);
    __half2 m1 = __floats2half2_rn(val.z, val.w);
    uint2 packed;
    packed.x = *(unsigned*)&m0;
    packed.y = *(unsigned*)&m1;
    ((uint2*)hh)[idx] = packed;
}

// per-block LDS histogram of its fixed edge range -> blockhist[bin][block]
__global__ void hist2_kernel(const int* __restrict__ dst, int* __restrict__ blockhist) {
    __shared__ int hist[NBINS];
    for (int i = threadIdx.x; i < NBINS; i += 256) hist[i] = 0;
    __syncthreads();
    int b = blockIdx.x;
    int e0 = b * EPB, e1 = min(e0 + EPB, N_EDGES);
    for (int e = e0 + threadIdx.x; e < e1; e += 256)
        atomicAdd(&hist[dst[e] >> 7], 1);
    __syncthreads();
    for (int i = threadIdx.x; i < NBINS; i += 256)
        blockhist[i * NSCB + b] = hist[i];
}

// one block per bin: exclusive scan of its 512 block-counts -> gofs; total per bin
__global__ void binreduce_kernel(const int* __restrict__ blockhist,
                                 int* __restrict__ gofs, int* __restrict__ total) {
    __shared__ int sm[NSCB];
    int bin = blockIdx.x;
    int i = threadIdx.x;   // 0..511
    int orig = blockhist[bin * NSCB + i];
    sm[i] = orig;
    __syncthreads();
    for (int off = 1; off < NSCB; off <<= 1) {
        int val = sm[i];
        if (i >= off) val += sm[i - off];
        __syncthreads();
        sm[i] = val;
        __syncthreads();
    }
    gofs[bin * NSCB + i] = sm[i] - orig;   // exclusive within bin
    if (i == NSCB - 1) total[bin] = sm[i];
}

// scan 782 bin totals -> binoff (exclusive); zeroes BN stats; packs W frags
// (wpack folded in: frag slot=(nt*2+kh)*64+lane, elem j = W[kh*32+(lane>>4)*8+j][nt*16+(lane&15)])
__global__ void binscan_kernel(const int* __restrict__ total,
                               int* __restrict__ binoff, float* __restrict__ stats,
                               const float* __restrict__ conv_W,
                               _Float16* __restrict__ wfrag) {
    __shared__ int sm[1024];
    int i = threadIdx.x;
    if (i < 6 * EMBED) stats[i] = 0.0f;
    // folded wpack: 3 layers x 512 slots
    for (int s = i; s < 3 * 512; s += 1024) {
        int L = s >> 9, slot = s & 511;
        int lane = slot & 63;
        int f = slot >> 6;          // nt*2+kh
        int nt = f >> 1, kh = f & 1;
        int n  = nt * 16 + (lane & 15);
        int k0 = kh * 32 + (lane >> 4) * 8;
        const float* W = conv_W + L * 4096;
        _Float16* out = wfrag + L * 4096;
#pragma unroll
        for (int j = 0; j < 8; ++j)
            out[slot * 8 + j] = (_Float16)W[(k0 + j) * 64 + n];
    }
    int orig = (i < NBINS) ? total[i] : 0;
    sm[i] = orig;
    __syncthreads();
    for (int off = 1; off < 1024; off <<= 1) {
        int val = sm[i];
        if (i >= off) val += sm[i - off];
        __syncthreads();
        sm[i] = val;
        __syncthreads();
    }
    if (i < NBINS) binoff[i] = sm[i] - orig;
    if (i == 0) binoff[NBINS] = N_EDGES;
}

// deterministic multisplit scatter: LDS cursors seeded from binoff+gofs.
// ZERO global atomics (R12: contention, not traffic, is the cost).
__global__ void binscatter_kernel(const int* __restrict__ src, const int* __restrict__ dst,
                                  const int* __restrict__ efeat,
                                  const int* __restrict__ binoff, const int* __restrict__ gofs,
                                  unsigned* __restrict__ binned) {
    __shared__ int cur[NBINS];
    int b = blockIdx.x;
    for (int i = threadIdx.x; i < NBINS; i += 256)
        cur[i] = binoff[i] + gofs[i * NSCB + b];
    __syncthreads();
    int e0 = b * EPB, e1 = min(e0 + EPB, N_EDGES);
    for (int e = e0 + threadIdx.x; e < e1; e += 256) {
        int t = dst[e];
        int bin = t >> 7;
        int pos = atomicAdd(&cur[bin], 1);   // LDS atomic
        binned[pos] = (unsigned)src[e] | ((unsigned)efeat[e] << 17)
                    | ((unsigned)(t & 127) << 20);
    }
}

// one block per bin: local deg count + local scan -> rowptr slice + ebuf region
__global__ void bincsr_kernel(const unsigned* __restrict__ binned,
                              const int* __restrict__ binoff,
                              int* __restrict__ rowptr,
                              unsigned* __restrict__ ebuf) {
    __shared__ int cnt[128];
    __shared__ int sc[128];
    int b = blockIdx.x;
    int tid = threadIdx.x;
    int base = binoff[b], end = binoff[b + 1];

    if (tid < 128) cnt[tid] = 0;
    __syncthreads();

    for (int i = base + tid; i < end; i += 256)
        atomicAdd(&cnt[binned[i] >> 20], 1);
    __syncthreads();

    if (tid < 128) sc[tid] = cnt[tid];
    __syncthreads();
    for (int off = 1; off < 128; off <<= 1) {
        int val = 0;
        if (tid < 128) {
            val = sc[tid];
            if (tid >= off) val += sc[tid - off];
        }
        __syncthreads();
        if (tid < 128) sc[tid] = val;
        __syncthreads();
    }
    if (tid < 128) {
        int excl = sc[tid] - cnt[tid];
        int v = b * 128 + tid;
        if (v < N_NODES) rowptr[v] = base + excl;
        cnt[tid] = excl;   // becomes running cursor
    }
    if (b == 0 && tid == 255) rowptr[N_NODES] = N_EDGES;
    __syncthreads();

    for (int i = base + tid; i < end; i += 256) {
        unsigned rec = binned[i];
        int dl = rec >> 20;
        int pos = base + atomicAdd(&cnt[dl], 1);
        // final payload format for gather: src(17b) | efeat<<20
        ebuf[pos] = (rec & 0x1FFFFu) | (((rec >> 17) & 0x7u) << 20);
    }
}

// ---------------- per-layer kernels ----------------

// Gather: quarter-wave per node (16 lanes x uint2 = 128B fp16 row per edge),
// 4 interleaved chains. Confirmed at the random-line service-rate wall:
// R6 (bytes/2 at const lines: no change), R10 (2x depth: no change), R18
// (eighth-wave: regression). Structural at ~50us/layer.
__launch_bounds__(256, 6)
__global__ void gather_kernel(const int* __restrict__ rowptr,
                              const unsigned* __restrict__ ebuf,
                              const float* __restrict__ bond,    // [5,64]
                              const __half* __restrict__ hh,     // fp16 mirror
                              const float* __restrict__ hmast,   // fp32 master
                              __half* __restrict__ t16) {
    __shared__ float bond_s[5 * EMBED];
    for (int i = threadIdx.x; i < 5 * EMBED; i += 256) bond_s[i] = bond[i];
    __syncthreads();

    int sl = threadIdx.x & 15;    // uint2 slot: dims 4sl..4sl+3
    int d0 = sl * 4;
    int gq = (blockIdx.x * 256 + threadIdx.x) >> 4;   // global quarter id
    int nq = (gridDim.x * 256) >> 4;
    const uint2* hhq = (const uint2*)hh;    // 16 uint2 per node row

    for (int v = gq; v < N_NODES; v += nq) {
        int rb = rowptr[v], re = rowptr[v + 1];
        float4 a0 = {0,0,0,0}, a1 = {0,0,0,0}, a2 = {0,0,0,0}, a3 = {0,0,0,0};
        int e = rb;
        for (; e + 4 <= re; e += 4) {
            unsigned p0 = ebuf[e + 0];
            unsigned p1 = ebuf[e + 1];
            unsigned p2 = ebuf[e + 2];
            unsigned p3 = ebuf[e + 3];
            uint2 g0 = hhq[(size_t)(p0 & 0xFFFFFu) * 16 + sl];
            uint2 g1 = hhq[(size_t)(p1 & 0xFFFFFu) * 16 + sl];
            uint2 g2 = hhq[(size_t)(p2 & 0xFFFFFu) * 16 + sl];
            uint2 g3 = hhq[(size_t)(p3 & 0xFFFFFu) * 16 + sl];
            const float* c0 = &bond_s[(p0 >> 20) * EMBED + d0];
            const float* c1 = &bond_s[(p1 >> 20) * EMBED + d0];
            const float* c2 = &bond_s[(p2 >> 20) * EMBED + d0];
            const float* c3 = &bond_s[(p3 >> 20) * EMBED + d0];
            float2 f0a = __half22float2(*(const __half2*)&g0.x);
            float2 f0b = __half22float2(*(const __half2*)&g0.y);
            float2 f1a = __half22float2(*(const __half2*)&g1.x);
            float2 f1b = __half22float2(*(const __half2*)&g1.y);
            float2 f2a = __half22float2(*(const __half2*)&g2.x);
            float2 f2b = __half22float2(*(const __half2*)&g2.y);
            float2 f3a = __half22float2(*(const __half2*)&g3.x);
            float2 f3b = __half22float2(*(const __half2*)&g3.y);
            a0.x += fmaxf(f0a.x + c0[0], 0.f); a0.y += fmaxf(f0a.y + c0[1], 0.f);
            a0.z += fmaxf(f0b.x + c0[2], 0.f); a0.w += fmaxf(f0b.y + c0[3], 0.f);
            a1.x += fmaxf(f1a.x + c1[0], 0.f); a1.y += fmaxf(f1a.y + c1[1], 0.f);
            a1.z += fmaxf(f1b.x + c1[2], 0.f); a1.w += fmaxf(f1b.y + c1[3], 0.f);
            a2.x += fmaxf(f2a.x + c2[0], 0.f); a2.y += fmaxf(f2a.y + c2[1], 0.f);
            a2.z += fmaxf(f2b.x + c2[2], 0.f); a2.w += fmaxf(f2b.y + c2[3], 0.f);
            a3.x += fmaxf(f3a.x + c3[0], 0.f); a3.y += fmaxf(f3a.y + c3[1], 0.f);
            a3.z += fmaxf(f3b.x + c3[2], 0.f); a3.w += fmaxf(f3b.y + c3[3], 0.f);
        }
        for (; e < re; ++e) {
            unsigned p = ebuf[e];
            uint2 g = hhq[(size_t)(p & 0xFFFFFu) * 16 + sl];
            const float* c = &bond_s[(p >> 20) * EMBED + d0];
            float2 fa = __half22float2(*(const __half2*)&g.x);
            float2 fb = __half22float2(*(const __half2*)&g.y);
            a0.x += fmaxf(fa.x + c[0], 0.f); a0.y += fmaxf(fa.y + c[1], 0.f);
            a0.z += fmaxf(fb.x + c[2], 0.f); a0.w += fmaxf(fb.y + c[3], 0.f);
        }
        float inv = 1.0f / fmaxf((float)(re - rb), 1.0f);
        float4 hr = ((const float4*)hmast)[(size_t)v * 16 + sl];
        float tx = (a0.x + a1.x + a2.x + a3.x) * inv + hr.x;
        float ty = (a0.y + a1.y + a2.y + a3.y) * inv + hr.y;
        float tz = (a0.z + a1.z + a2.z + a3.z) * inv + hr.z;
        float tw = (a0.w + a1.w + a2.w + a3.w) * inv + hr.w;
        __half2 m0 = __floats2half2_rn(tx, ty);
        __half2 m1 = __floats2half2_rn(tz, tw);
        uint2 packed;
        packed.x = *(unsigned*)&m0;
        packed.y = *(unsigned*)&m1;
        ((uint2*)t16)[(size_t)v * 16 + sl] = packed;
    }
}

// MFMA GEMM: wave = 16 nodes; W fragments loop-invariant in registers
// (R13-R15 were all ~50us bound on W operand re-fetch through LDS/L1).
// h_pre stored fp16. C/D layout: col=lane&15, row=(lane>>4)*4+reg [m89].
__launch_bounds__(256)
__global__ void gemm_mfma_kernel(const _Float16* __restrict__ t16,
                                 const _Float16* __restrict__ wfrag,  // packed
                                 const float* __restrict__ bias,
                                 __half* __restrict__ h_pre16,
                                 float* __restrict__ colsum,
                                 float* __restrict__ colsq) {
    __shared__ float red[4][8][16];

    int lane = threadIdx.x & 63;
    int wblk = threadIdx.x >> 6;
    int quad = lane >> 4;
    int col  = lane & 15;

    half8 bf[4][2];
#pragma unroll
    for (int nt = 0; nt < 4; ++nt)
#pragma unroll
        for (int kh = 0; kh < 2; ++kh)
            bf[nt][kh] = *(const half8*)(wfrag + ((size_t)(nt * 2 + kh) * 64 + lane) * 8);

    float bj[4];
#pragma unroll
    for (int nt = 0; nt < 4; ++nt) bj[nt] = bias[nt * 16 + col];

    float lsum[4] = {0.f, 0.f, 0.f, 0.f};
    float lsq [4] = {0.f, 0.f, 0.f, 0.f};

    for (int tile = blockIdx.x * 4 + wblk; tile < NTILES; tile += gridDim.x * 4) {
        int base = tile * 16;
        const _Float16* arow = t16 + (size_t)(base + col) * 64 + quad * 8;
        half8 a0 = *(const half8*)(arow);
        half8 a1 = *(const half8*)(arow + 32);

#pragma unroll
        for (int nt = 0; nt < 4; ++nt) {
            floatx4 c = {bj[nt], bj[nt], bj[nt], bj[nt]};
            c = __builtin_amdgcn_mfma_f32_16x16x32_f16(a0, bf[nt][0], c, 0, 0, 0);
            c = __builtin_amdgcn_mfma_f32_16x16x32_f16(a1, bf[nt][1], c, 0, 0, 0);
#pragma unroll
            for (int r = 0; r < 4; ++r) {
                float val = c[r];
                h_pre16[(size_t)(base + quad * 4 + r) * 64 + nt * 16 + col] = __float2half(val);
                lsum[nt] += val;
                lsq[nt]  += val * val;
            }
        }
    }

#pragma unroll
    for (int nt = 0; nt < 4; ++nt) {
        lsum[nt] += __shfl_xor(lsum[nt], 16); lsum[nt] += __shfl_xor(lsum[nt], 32);
        lsq[nt]  += __shfl_xor(lsq[nt], 16);  lsq[nt]  += __shfl_xor(lsq[nt], 32);
    }
    if (lane < 16) {
#pragma unroll
        for (int nt = 0; nt < 4; ++nt) {
            red[wblk][nt * 2 + 0][lane] = lsum[nt];
            red[wblk][nt * 2 + 1][lane] = lsq[nt];
        }
    }
    __syncthreads();
    if (threadIdx.x < 128) {
        int f = threadIdx.x >> 4, l = threadIdx.x & 15;
        float s = red[0][f][l] + red[1][f][l] + red[2][f][l] + red[3][f][l];
        int nt = f >> 1;
        if ((f & 1) == 0) atomicAdd(&colsum[nt * 16 + l], s);
        else              atomicAdd(&colsq[nt * 16 + l], s);
    }
}

// batchnorm + relu + residual (layers 0,1): reads fp16 h_pre, updates fp32 h + fp16 mirror
__global__ void bn_kernel(const __half* __restrict__ h_pre16,
                          const float* __restrict__ colsum,
                          const float* __restrict__ colsq,
                          const float* __restrict__ gamma,
                          const float* __restrict__ beta,
                          float4* __restrict__ h4,
                          __half* __restrict__ hh) {
    int idx = blockIdx.x * blockDim.x + threadIdx.x;   // 4 dims each
    if (idx >= N_NODES * 16) return;
    int q = idx & 15;            // dims 4q..4q+3
    const float invN = 1.0f / (float)N_NODES;
    uint2 pr = ((const uint2*)h_pre16)[idx];
    float2 pa = __half22float2(*(const __half2*)&pr.x);
    float2 pb = __half22float2(*(const __half2*)&pr.y);
    float4 r = h4[idx];
    float o[4] = {pa.x, pa.y, pb.x, pb.y};
    float rr[4] = {r.x, r.y, r.z, r.w};
#pragma unroll
    for (int c = 0; c < 4; ++c) {
        int j = q * 4 + c;
        float mu  = colsum[j] * invN;
        float var = colsq[j] * invN - mu * mu;
        float inv = rsqrtf(var + BN_EPS);
        float y = (o[c] - mu) * inv * gamma[j] + beta[j];
        y = fmaxf(y, 0.0f);                  // layers 0,1 always relu
        o[c] = y + rr[c];
    }
    float4 res = {o[0], o[1], o[2], o[3]};
    h4[idx] = res;
    __half2 m0 = __floats2half2_rn(res.x, res.y);
    __half2 m1 = __floats2half2_rn(res.z, res.w);
    uint2 packed;
    packed.x = *(unsigned*)&m0;
    packed.y = *(unsigned*)&m1;
    ((uint2*)hh)[idx] = packed;
}

// fused layer-2 bn + pool + pred: one block (128 threads) per graph.
// Final h never materialized: mean_g over [bn2(h_pre[v]) + h[v]].
__global__ void poolpred_kernel(const int* __restrict__ gstart,
                                const __half* __restrict__ h_pre16,
                                const float* __restrict__ h,
                                const float* __restrict__ colsum,   // layer 2 slice
                                const float* __restrict__ colsq,
                                const float* __restrict__ gamma,
                                const float* __restrict__ beta,
                                const float* __restrict__ W,   // [64,128]
                                const float* __restrict__ b,   // [128]
                                float* __restrict__ out) {
    __shared__ float gm[EMBED];
    int g = blockIdx.x;
    int j = threadIdx.x;  // 0..127
    int nb = gstart[g], ne = gstart[g + 1];
    if (j < EMBED) {
        const float invN = 1.0f / (float)N_NODES;
        float mu  = colsum[j] * invN;
        float var = colsq[j] * invN - mu * mu;
        float inv = rsqrtf(var + BN_EPS);
        float gam = gamma[j], bet = beta[j];
        float s = 0.0f;
        for (int v = nb; v < ne; ++v) {
            float p = __half2float(h_pre16[(size_t)v * EMBED + j]);
            float y = (p - mu) * inv * gam + bet;       // no relu on last layer
            s += y + h[(size_t)v * EMBED + j];
        }
        gm[j] = s / fmaxf((float)(ne - nb), 1.0f);
    }
    __syncthreads();
    float acc = b[j];
#pragma unroll
    for (int d = 0; d < EMBED; ++d)
        acc += gm[d] * W[d * OUT_DIM + j];
    out[g * OUT_DIM + j] = acc;
}

// ---------------- launch ----------------

extern "C" void kernel_launch(void* const* d_in, const int* in_sizes, int n_in,
                              void* d_out, int out_size, void* d_ws, size_t ws_size,
                              hipStream_t stream) {
    const int*   nfeat      = (const int*)d_in[0];
    const int*   efeat      = (const int*)d_in[1];
    const int*   src        = (const int*)d_in[2];
    const int*   dst        = (const int*)d_in[3];
    const int*   gid        = (const int*)d_in[4];
    const float* atom_embed = (const float*)d_in[5];
    const float* bond_embed = (const float*)d_in[6];  // [3,5,64]
    const float* conv_W     = (const float*)d_in[7];  // [3,64,64]
    const float* conv_b     = (const float*)d_in[8];  // [3,64]
    const float* bn_gamma   = (const float*)d_in[9];  // [3,64]
    const float* bn_beta    = (const float*)d_in[10]; // [3,64]
    const float* pred_W     = (const float*)d_in[11]; // [64,128]
    const float* pred_b     = (const float*)d_in[12]; // [128]
    float* out = (float*)d_out;

    char* wsb = (char*)d_ws;
    float*     h        = (float*)wsb;                  wsb += (size_t)N_NODES * EMBED * 4;
    __half*    h_pre16  = (__half*)wsb;                 wsb += (size_t)N_NODES * EMBED * 2;
    _Float16*  t16      = (_Float16*)wsb;               wsb += (size_t)N_NODES * EMBED * 2;
    __half*    hh       = (__half*)wsb;                 wsb += (size_t)N_NODES * EMBED * 2;
    _Float16*  wfrag    = (_Float16*)wsb;               wsb += (size_t)3 * 4096 * 2;
    unsigned*  binned   = (unsigned*)wsb;               wsb += (size_t)N_EDGES * 4;
    unsigned*  ebuf     = (unsigned*)wsb;               wsb += (size_t)N_EDGES * 4;
    int*       blockhist= (int*)wsb;                    wsb += (size_t)NBINS * NSCB * 4;
    int*       gofs     = (int*)wsb;                    wsb += (size_t)NBINS * NSCB * 4;
    int*       total    = (int*)wsb;                    wsb += (size_t)NBINS * 4;
    int*       binoff   = (int*)wsb;                    wsb += (size_t)(NBINS + 1) * 4;
    int*       rowptr   = (int*)wsb;                    wsb += (size_t)(N_NODES + 1) * 4;
    int*       gstart   = (int*)wsb;                    wsb += (size_t)(N_GRAPHS + 1) * 4;
    float*     colsum   = (float*)wsb;                  wsb += (size_t)3 * EMBED * 4;
    float*     colsq    = (float*)wsb;                  wsb += (size_t)3 * EMBED * 4;

    embed_kernel<<<(N_NODES * 16 + 255) / 256, 256, 0, stream>>>(
        nfeat, atom_embed, (float4*)h, hh, gid, gstart);
    hist2_kernel<<<NSCB, 256, 0, stream>>>(dst, blockhist);
    binreduce_kernel<<<NBINS, NSCB, 0, stream>>>(blockhist, gofs, total);
    binscan_kernel<<<1, 1024, 0, stream>>>(total, binoff, colsum, conv_W, wfrag);
    binscatter_kernel<<<NSCB, 256, 0, stream>>>(src, dst, efeat, binoff, gofs, binned);
    bincsr_kernel<<<NBINS, 256, 0, stream>>>(binned, binoff, rowptr, ebuf);

    for (int i = 0; i < 3; ++i) {
        gather_kernel<<<1536, 256, 0, stream>>>(
            rowptr, ebuf, bond_embed + i * 5 * EMBED, hh, h, (__half*)t16);
        gemm_mfma_kernel<<<1024, 256, 0, stream>>>(
            t16, wfrag + (size_t)i * 4096, conv_b + i * EMBED,
            h_pre16, colsum + i * EMBED, colsq + i * EMBED);
        if (i != 2) {
            bn_kernel<<<(N_NODES * 16 + 255) / 256, 256, 0, stream>>>(
                h_pre16, colsum + i * EMBED, colsq + i * EMBED,
                bn_gamma + i * EMBED, bn_beta + i * EMBED,
                (float4*)h, hh);
        }
    }

    poolpred_kernel<<<N_GRAPHS, OUT_DIM, 0, stream>>>(
        gstart, h_pre16, h, colsum + 2 * EMBED, colsq + 2 * EMBED,
        bn_gamma + 2 * EMBED, bn_beta + 2 * EMBED, pred_W, pred_b, out);
}